// Round 1
// baseline (390.412 us; speedup 1.0000x reference)
//
#include <hip/hip_runtime.h>
#include <math.h>

#define B_DIM 4
#define T_DIM 2048
#define E_DIM 1024
#define D_DIM 4
#define M_ROWS (B_DIM*T_DIM)   /* 8192 */
#define NC 16                  /* scan chunks per sequence */
#define CL (T_DIM/NC)          /* 128 */

typedef short short8 __attribute__((ext_vector_type(8)));
typedef float f32x4 __attribute__((ext_vector_type(4)));

__device__ __forceinline__ float bf2f(unsigned short u){
  union { unsigned int i; float f; } c; c.i = ((unsigned int)u) << 16; return c.f;
}
__device__ __forceinline__ unsigned short f2bf(float f){
  union { float f; unsigned int i; } c; c.f = f;
  unsigned int u = c.i;
  return (unsigned short)((u + 0x7FFFu + ((u >> 16) & 1u)) >> 16);
}
__device__ __forceinline__ float sigf(float x){ return 1.f/(1.f+__expf(-x)); }
__device__ __forceinline__ float geluf(float x){ return 0.5f*x*(1.f+erff(x*0.70710678118f)); }

// ---------------- converts ----------------
__global__ __launch_bounds__(256) void conv_w_k(const float* __restrict__ s,
                                                unsigned short* __restrict__ d, int n){
  int i = (blockIdx.x*256 + threadIdx.x)*4;
  if (i >= n) return;
  float4 v = *(const float4*)&s[i];
  uint2 p;
  p.x = (unsigned int)f2bf(v.x) | ((unsigned int)f2bf(v.y) << 16);
  p.y = (unsigned int)f2bf(v.z) | ((unsigned int)f2bf(v.w) << 16);
  *(uint2*)&d[i] = p;
}

// x (M x 1024 f32) -> gatein cols [0,1024) of (M x 2048 bf16)
__global__ __launch_bounds__(256) void conv_x_k(const float* __restrict__ x,
                                                unsigned short* __restrict__ gatein){
  int gid = blockIdx.x*256 + threadIdx.x;        // per 4 elements
  int idx = gid*4;
  int m = idx >> 10, c = idx & 1023;
  float4 v = *(const float4*)&x[idx];
  uint2 p;
  p.x = (unsigned int)f2bf(v.x) | ((unsigned int)f2bf(v.y) << 16);
  p.y = (unsigned int)f2bf(v.z) | ((unsigned int)f2bf(v.w) << 16);
  *(uint2*)&gatein[(size_t)m*2048 + c] = p;
}

// ---------------- ctx EMA (chunked 2-pass scan) ----------------
__global__ __launch_bounds__(256) void ctx_carry_k(const float* __restrict__ x,
                                                   const float* __restrict__ tau_ctx,
                                                   float* __restrict__ car){
  int gid = blockIdx.x*256 + threadIdx.x;        // B*NC*E = 65536
  int e = gid & 1023, bc = gid >> 10;
  int b = bc >> 4, chunk = bc & 15;
  float alpha = 1.f/(1.f+expf(tau_ctx[0]));
  const float* xp = x + ((size_t)b*T_DIM + chunk*CL)*E_DIM + e;
  float h = 0.f;
  #pragma unroll 8
  for (int t = 0; t < CL; t++) h = alpha*h + xp[(size_t)t*E_DIM];
  car[(size_t)bc*E_DIM + e] = h;
}

__global__ __launch_bounds__(256) void ctx_scan_k(const float* __restrict__ x,
                                                  const float* __restrict__ tau_ctx,
                                                  const float* __restrict__ car,
                                                  unsigned short* __restrict__ gatein){
  int gid = blockIdx.x*256 + threadIdx.x;
  int e = gid & 1023, bc = gid >> 10;
  int b = bc >> 4, chunk = bc & 15;
  float alpha = 1.f/(1.f+expf(tau_ctx[0]));
  float alphaL = powf(alpha, (float)CL);
  float h = 0.f;
  for (int j = 0; j < chunk; j++) h = alphaL*h + car[(size_t)(b*NC + j)*E_DIM + e];
  const float* xp = x + ((size_t)b*T_DIM + chunk*CL)*E_DIM + e;
  unsigned short* op = gatein + ((size_t)(b*T_DIM + chunk*CL))*2048 + 1024 + e;
  #pragma unroll 8
  for (int t = 0; t < CL; t++){
    h = alpha*h + xp[(size_t)t*E_DIM];
    op[(size_t)t*2048] = f2bf(h);
  }
}

// ---------------- dendrite EMAs (chunked 2-pass), fused blend ----------------
__global__ __launch_bounds__(256) void dend_carry_k(const unsigned short* __restrict__ gated,
                                                    const float* __restrict__ mod,
                                                    const float* __restrict__ tau_raws,
                                                    float* __restrict__ car){
  int gid = blockIdx.x*256 + threadIdx.x;
  int e = gid & 1023, bc = gid >> 10;
  int b = bc >> 4, chunk = bc & 15;
  float a0 = 1.f/(1.f+expf(tau_raws[0]));
  float a1 = 1.f/(1.f+expf(tau_raws[1]));
  float a2 = 1.f/(1.f+expf(tau_raws[2]));
  float a3 = 1.f/(1.f+expf(tau_raws[3]));
  const unsigned short* gp = gated + ((size_t)(b*T_DIM + chunk*CL))*E_DIM + e;
  const float* mp = mod + (size_t)(b*T_DIM + chunk*CL)*4;
  float h0=0.f,h1=0.f,h2=0.f,h3=0.f;
  #pragma unroll 4
  for (int t = 0; t < CL; t++){
    float g = bf2f(gp[(size_t)t*E_DIM]);
    float4 m4 = *(const float4*)&mp[t*4];
    h0 = a0*h0 + g*m4.x; h1 = a1*h1 + g*m4.y; h2 = a2*h2 + g*m4.z; h3 = a3*h3 + g*m4.w;
  }
  size_t base = (size_t)bc*E_DIM + e;
  car[0*65536 + base] = h0; car[1*65536 + base] = h1;
  car[2*65536 + base] = h2; car[3*65536 + base] = h3;
}

__global__ __launch_bounds__(256) void dend_scan_k(const unsigned short* __restrict__ gated,
                                                   const float* __restrict__ mod,
                                                   const float* __restrict__ tau_raws,
                                                   const float* __restrict__ car,
                                                   const float* __restrict__ blend,
                                                   unsigned short* __restrict__ temporal){
  int gid = blockIdx.x*256 + threadIdx.x;
  int e = gid & 1023, bc = gid >> 10;
  int b = bc >> 4, chunk = bc & 15;
  float al[4], hh[4];
  #pragma unroll
  for (int d = 0; d < 4; d++){ al[d] = 1.f/(1.f+expf(tau_raws[d])); hh[d] = 0.f; }
  #pragma unroll
  for (int d = 0; d < 4; d++){
    float aL = powf(al[d], (float)CL);
    float h = 0.f;
    for (int j = 0; j < chunk; j++) h = aL*h + car[(size_t)d*65536 + (size_t)(b*NC + j)*E_DIM + e];
    hh[d] = h;
  }
  // blend softmax over d for this channel e
  float bl[4];
  #pragma unroll
  for (int d = 0; d < 4; d++) bl[d] = blend[d*E_DIM + e];
  float mx = fmaxf(fmaxf(bl[0],bl[1]), fmaxf(bl[2],bl[3]));
  float ex0=__expf(bl[0]-mx), ex1=__expf(bl[1]-mx), ex2=__expf(bl[2]-mx), ex3=__expf(bl[3]-mx);
  float inv = 1.f/(ex0+ex1+ex2+ex3);
  float w0=ex0*inv, w1=ex1*inv, w2=ex2*inv, w3=ex3*inv;

  const unsigned short* gp = gated + ((size_t)(b*T_DIM + chunk*CL))*E_DIM + e;
  const float* mp = mod + (size_t)(b*T_DIM + chunk*CL)*4;
  unsigned short* op = temporal + ((size_t)(b*T_DIM + chunk*CL))*E_DIM + e;
  float h0=hh[0], h1=hh[1], h2=hh[2], h3=hh[3];
  float a0=al[0], a1=al[1], a2=al[2], a3=al[3];
  #pragma unroll 4
  for (int t = 0; t < CL; t++){
    float g = bf2f(gp[(size_t)t*E_DIM]);
    float4 m4 = *(const float4*)&mp[t*4];
    h0 = a0*h0 + g*m4.x; h1 = a1*h1 + g*m4.y; h2 = a2*h2 + g*m4.z; h3 = a3*h3 + g*m4.w;
    float tv = w0*h0 + w1*h1 + w2*h2 + w3*h3;
    op[(size_t)t*E_DIM] = f2bf(tv);
  }
}

// ---------------- mod = 0.5 + sigmoid(h1 @ Wn2^T + bn2) ----------------
__global__ __launch_bounds__(256) void mod_k(const unsigned short* __restrict__ h1,
                                             const float* __restrict__ Wn2,
                                             const float* __restrict__ bn2,
                                             float* __restrict__ mod){
  int wave = threadIdx.x >> 6, lane = threadIdx.x & 63;
  int m = blockIdx.x*4 + wave;
  float p0=0.f,p1=0.f,p2=0.f,p3=0.f;
  for (int c = lane; c < 256; c += 64){
    float h = bf2f(h1[(size_t)m*256 + c]);
    p0 += h*Wn2[0*256 + c]; p1 += h*Wn2[1*256 + c];
    p2 += h*Wn2[2*256 + c]; p3 += h*Wn2[3*256 + c];
  }
  #pragma unroll
  for (int off = 32; off > 0; off >>= 1){
    p0 += __shfl_down(p0, off); p1 += __shfl_down(p1, off);
    p2 += __shfl_down(p2, off); p3 += __shfl_down(p3, off);
  }
  if (lane == 0){
    mod[(size_t)m*4 + 0] = 0.5f + sigf(p0 + bn2[0]);
    mod[(size_t)m*4 + 1] = 0.5f + sigf(p1 + bn2[1]);
    mod[(size_t)m*4 + 2] = 0.5f + sigf(p2 + bn2[2]);
    mod[(size_t)m*4 + 3] = 0.5f + sigf(p3 + bn2[3]);
  }
}

// ---------------- bf16 MFMA GEMM: out[m,n] = sum_k A[m,k]*W[n,k] ----------------
// EPI: 0 = sigmoid(+bias)*x -> bf16 (gated); 1 = gelu(+bias) -> bf16;
//      2 = sigmoid(+bias)*ebf -> bf16 (sg);  3 = plain f32
#define BM 128
#define BN 128
#define BK 32

template<int EPI>
__global__ __launch_bounds__(256, 2) void gemm_bf16_k(
    const unsigned short* __restrict__ A, int lda,
    const unsigned short* __restrict__ Bw,
    int K, int N,
    const float* __restrict__ bias,
    const float* __restrict__ xf32,
    const unsigned short* __restrict__ ebf,
    void* __restrict__ outp)
{
  __shared__ unsigned short sA[BM*BK];
  __shared__ unsigned short sB[BN*BK];
  const int tid = threadIdx.x;
  const int row0 = blockIdx.x * BM;
  const int col0 = blockIdx.y * BN;
  const int wave = tid >> 6, lane = tid & 63;
  const int quad = lane >> 4, l15 = lane & 15;
  const int wm = (wave & 1) * 64, wn = (wave >> 1) * 64;

  f32x4 acc[4][4];
  #pragma unroll
  for (int i = 0; i < 4; i++)
    #pragma unroll
    for (int j = 0; j < 4; j++) acc[i][j] = (f32x4){0.f,0.f,0.f,0.f};

  const int r0 = tid >> 2;               // rows 0..63
  const int r1 = (tid + 256) >> 2;       // rows 64..127
  const int kc = (tid & 3) * 8;

  for (int k0 = 0; k0 < K; k0 += BK){
    uint4 ga0 = *(const uint4*)&A [(size_t)(row0 + r0)*lda + k0 + kc];
    uint4 ga1 = *(const uint4*)&A [(size_t)(row0 + r1)*lda + k0 + kc];
    uint4 gb0 = *(const uint4*)&Bw[(size_t)(col0 + r0)*K   + k0 + kc];
    uint4 gb1 = *(const uint4*)&Bw[(size_t)(col0 + r1)*K   + k0 + kc];
    __syncthreads();
    *(uint4*)&sA[(size_t)tid*8]       = ga0;
    *(uint4*)&sA[(size_t)(tid+256)*8] = ga1;
    *(uint4*)&sB[(size_t)tid*8]       = gb0;
    *(uint4*)&sB[(size_t)(tid+256)*8] = gb1;
    __syncthreads();
    short8 afr[4], bfr[4];
    #pragma unroll
    for (int i = 0; i < 4; i++) afr[i] = *(const short8*)&sA[(wm + i*16 + l15)*BK + quad*8];
    #pragma unroll
    for (int j = 0; j < 4; j++) bfr[j] = *(const short8*)&sB[(wn + j*16 + l15)*BK + quad*8];
    #pragma unroll
    for (int i = 0; i < 4; i++)
      #pragma unroll
      for (int j = 0; j < 4; j++)
        acc[i][j] = __builtin_amdgcn_mfma_f32_16x16x32_bf16(afr[i], bfr[j], acc[i][j], 0, 0, 0);
  }

  #pragma unroll
  for (int i = 0; i < 4; i++){
    #pragma unroll
    for (int j = 0; j < 4; j++){
      const int col = col0 + wn + j*16 + l15;
      #pragma unroll
      for (int r = 0; r < 4; r++){
        const int row = row0 + wm + i*16 + quad*4 + r;
        float v = acc[i][j][r];
        size_t o = (size_t)row * N + col;
        if (EPI == 0){
          v += bias[col];
          float wg = sigf(v);
          ((unsigned short*)outp)[o] = f2bf(xf32[o] * wg);
        } else if (EPI == 1){
          v += bias[col];
          ((unsigned short*)outp)[o] = f2bf(geluf(v));
        } else if (EPI == 2){
          v += bias[col];
          ((unsigned short*)outp)[o] = f2bf(sigf(v) * bf2f(ebf[o]));
        } else {
          ((float*)outp)[o] = v;
        }
      }
    }
  }
}

// ---------------- LayerNorm over E=1024 ----------------
__global__ __launch_bounds__(256) void ln_k(const float* __restrict__ in,
                                            const float* __restrict__ gamma,
                                            const float* __restrict__ beta,
                                            float* __restrict__ out){
  __shared__ float s1[4], s2[4];
  int row = blockIdx.x, tid = threadIdx.x;
  float4 v = *(const float4*)&in[(size_t)row*1024 + tid*4];
  float s = v.x+v.y+v.z+v.w;
  float q = v.x*v.x+v.y*v.y+v.z*v.z+v.w*v.w;
  #pragma unroll
  for (int off = 32; off > 0; off >>= 1){ s += __shfl_down(s, off); q += __shfl_down(q, off); }
  int wave = tid >> 6, lane = tid & 63;
  if (lane == 0){ s1[wave] = s; s2[wave] = q; }
  __syncthreads();
  s = s1[0]+s1[1]+s1[2]+s1[3];
  q = s2[0]+s2[1]+s2[2]+s2[3];
  float mu = s*(1.f/1024.f);
  float var = q*(1.f/1024.f) - mu*mu;
  float rs = rsqrtf(var + 1e-5f);
  int c = tid*4;
  float4 g = *(const float4*)&gamma[c];
  float4 bb = *(const float4*)&beta[c];
  float4 o;
  o.x = (v.x-mu)*rs*g.x + bb.x;
  o.y = (v.y-mu)*rs*g.y + bb.y;
  o.z = (v.z-mu)*rs*g.z + bb.z;
  o.w = (v.w-mu)*rs*g.w + bb.w;
  *(float4*)&out[(size_t)row*1024 + c] = o;
}

// ---------------- launch ----------------
extern "C" void kernel_launch(void* const* d_in, const int* in_sizes, int n_in,
                              void* d_out, int out_size, void* d_ws, size_t ws_size,
                              hipStream_t stream) {
  const float* x        = (const float*)d_in[0];
  const float* tau_ctx  = (const float*)d_in[1];
  const float* tau_raws = (const float*)d_in[2];
  const float* Wg       = (const float*)d_in[3];
  const float* bg       = (const float*)d_in[4];
  const float* Wn1      = (const float*)d_in[5];
  const float* bn1      = (const float*)d_in[6];
  const float* Wn2      = (const float*)d_in[7];
  const float* bn2      = (const float*)d_in[8];
  const float* blend    = (const float*)d_in[9];
  const float* Wsoma    = (const float*)d_in[10];
  const float* bsoma    = (const float*)d_in[11];
  const float* Wtemp    = (const float*)d_in[12];
  const float* btemp    = (const float*)d_in[13];
  const float* Wout     = (const float*)d_in[14];
  const float* gamma    = (const float*)d_in[15];
  const float* beta     = (const float*)d_in[16];

  char* ws = (char*)d_ws;
  // workspace layout (bytes)
  unsigned short* gatein   = (unsigned short*)(ws + 0);          // M x 2048 bf16 (33,554,432)
  float*          out_pre  = (float*)(ws + 0);                   // alias: M x 1024 f32 (same 32MB; gatein dead by then)
  unsigned short* wg_bf    = (unsigned short*)(ws + 33554432);   // 4,194,304
  unsigned short* wn1_bf   = (unsigned short*)(ws + 37748736);   // 524,288
  unsigned short* wsoma_bf = (unsigned short*)(ws + 38273024);   // 2,097,152
  unsigned short* wtemp_bf = (unsigned short*)(ws + 40370176);   // 2,097,152
  unsigned short* wout_bf  = (unsigned short*)(ws + 42467328);   // 2,097,152
  unsigned short* h1_bf    = (unsigned short*)(ws + 44564480);   // 4,194,304
  float*          modbuf   = (float*)(ws + 48758784);            // 131,072
  float*          car_ctx  = (float*)(ws + 48889856);            // 262,144
  float*          car_d    = (float*)(ws + 49152000);            // 1,048,576
  unsigned short* gated    = (unsigned short*)(ws + 50200576);   // 16,777,216
  unsigned short* sg       = gated;                              // alias (gated dead after dend scans)
  unsigned short* temporal = (unsigned short*)(ws + 66977792);   // 16,777,216
  unsigned short* soma     = (unsigned short*)(ws + 83755008);   // 16,777,216

  // 1) converts
  conv_x_k<<<dim3(M_ROWS*E_DIM/4/256), dim3(256), 0, stream>>>(x, gatein);
  conv_w_k<<<dim3(2048), dim3(256), 0, stream>>>(Wg,    wg_bf,    2097152);
  conv_w_k<<<dim3(256),  dim3(256), 0, stream>>>(Wn1,   wn1_bf,   262144);
  conv_w_k<<<dim3(1024), dim3(256), 0, stream>>>(Wsoma, wsoma_bf, 1048576);
  conv_w_k<<<dim3(1024), dim3(256), 0, stream>>>(Wtemp, wtemp_bf, 1048576);
  conv_w_k<<<dim3(1024), dim3(256), 0, stream>>>(Wout,  wout_bf,  1048576);

  // 2) ctx EMA -> gatein[:,1024:2048]
  ctx_carry_k<<<dim3(256), dim3(256), 0, stream>>>(x, tau_ctx, car_ctx);
  ctx_scan_k <<<dim3(256), dim3(256), 0, stream>>>(x, tau_ctx, car_ctx, gatein);

  // 3) gate GEMM: gated = x * sigmoid(gatein@Wg^T + bg)
  gemm_bf16_k<0><<<dim3(M_ROWS/BM, 1024/BN), dim3(256), 0, stream>>>(
      gatein, 2048, wg_bf, 2048, 1024, bg, x, nullptr, gated);

  // 4) h1 = gelu(x@Wn1^T + bn1)
  gemm_bf16_k<1><<<dim3(M_ROWS/BM, 256/BN), dim3(256), 0, stream>>>(
      gatein, 2048, wn1_bf, 1024, 256, bn1, nullptr, nullptr, h1_bf);

  // 5) mod
  mod_k<<<dim3(M_ROWS/4), dim3(256), 0, stream>>>(h1_bf, Wn2, bn2, modbuf);

  // 6) dendrite EMAs -> temporal
  dend_carry_k<<<dim3(256), dim3(256), 0, stream>>>(gated, modbuf, tau_raws, car_d);
  dend_scan_k <<<dim3(256), dim3(256), 0, stream>>>(gated, modbuf, tau_raws, car_d, blend, temporal);

  // 7) soma = gelu(x@Wsoma^T + bsoma)
  gemm_bf16_k<1><<<dim3(M_ROWS/BM, 1024/BN), dim3(256), 0, stream>>>(
      gatein, 2048, wsoma_bf, 1024, 1024, bsoma, nullptr, nullptr, soma);

  // 8) sg = soma * sigmoid(temporal@Wtemp^T + btemp)   (overwrites gated region)
  gemm_bf16_k<2><<<dim3(M_ROWS/BM, 1024/BN), dim3(256), 0, stream>>>(
      temporal, 1024, wtemp_bf, 1024, 1024, btemp, nullptr, soma, sg);

  // 9) out_pre = sg@Wout^T   (overwrites gatein region)
  gemm_bf16_k<3><<<dim3(M_ROWS/BM, 1024/BN), dim3(256), 0, stream>>>(
      sg, 1024, wout_bf, 1024, 1024, nullptr, nullptr, nullptr, out_pre);

  // 10) LayerNorm
  ln_k<<<dim3(M_ROWS), dim3(256), 0, stream>>>(out_pre, gamma, beta, (float*)d_out);
}

// Round 2
// 387.018 us; speedup vs baseline: 1.0088x; 1.0088x over previous
//
#include <hip/hip_runtime.h>
#include <math.h>

#define B_DIM 4
#define T_DIM 2048
#define E_DIM 1024
#define M_ROWS (B_DIM*T_DIM)   /* 8192 */
#define NC 32                  /* scan chunks per sequence */
#define CL (T_DIM/NC)          /* 64 */

typedef short short8 __attribute__((ext_vector_type(8)));
typedef float f32x4 __attribute__((ext_vector_type(4)));

__device__ __forceinline__ float bf2f(unsigned short u){
  union { unsigned int i; float f; } c; c.i = ((unsigned int)u) << 16; return c.f;
}
__device__ __forceinline__ unsigned short f2bf(float f){
  union { float f; unsigned int i; } c; c.f = f;
  unsigned int u = c.i;
  return (unsigned short)((u + 0x7FFFu + ((u >> 16) & 1u)) >> 16);
}
__device__ __forceinline__ unsigned int pack2(float a, float b){
  return (unsigned int)f2bf(a) | ((unsigned int)f2bf(b) << 16);
}
__device__ __forceinline__ float sigf(float x){ return 1.f/(1.f+__expf(-x)); }
__device__ __forceinline__ float geluf(float x){ return 0.5f*x*(1.f+erff(x*0.70710678118f)); }

__device__ __forceinline__ void glds16(const unsigned short* g, unsigned short* l){
  __builtin_amdgcn_global_load_lds((const __attribute__((address_space(1))) void*)g,
                                   (__attribute__((address_space(3))) void*)l, 16, 0, 0);
}

// ---------------- fused weight/bias converts ----------------
__device__ __forceinline__ void cvt4(const float* __restrict__ s, unsigned short* __restrict__ d){
  float4 v = *(const float4*)s;
  uint2 p; p.x = pack2(v.x, v.y); p.y = pack2(v.z, v.w);
  *(uint2*)d = p;
}

__global__ __launch_bounds__(256) void conv_all_k(
    const float* __restrict__ Wg, const float* __restrict__ Wsoma,
    const float* __restrict__ Wn1, const float* __restrict__ Wtemp,
    const float* __restrict__ Wout, const float* __restrict__ bsoma,
    const float* __restrict__ bn1,
    unsigned short* __restrict__ wg_bf, unsigned short* __restrict__ wsn1,
    unsigned short* __restrict__ wtemp_bf, unsigned short* __restrict__ wout_bf,
    float* __restrict__ bsn1){
  int u = blockIdx.x*256 + threadIdx.x;
  if (u < 524288){ cvt4(Wg + (size_t)u*4, wg_bf + (size_t)u*4); }
  else if (u < 786432){ u -= 524288; cvt4(Wsoma + (size_t)u*4, wsn1 + (size_t)u*4); }
  else if (u < 851968){ u -= 786432; cvt4(Wn1 + (size_t)u*4, wsn1 + 1048576 + (size_t)u*4); }
  else if (u < 1114112){ u -= 851968; cvt4(Wtemp + (size_t)u*4, wtemp_bf + (size_t)u*4); }
  else if (u < 1376256){ u -= 1114112; cvt4(Wout + (size_t)u*4, wout_bf + (size_t)u*4); }
  else if (u < 1376576){
    u -= 1376256; int i = u*4;
    float4 v = (i < 1024) ? *(const float4*)&bsoma[i] : *(const float4*)&bn1[i-1024];
    *(float4*)&bsn1[i] = v;
  }
}

// ---------------- ctx EMA (chunked 2-pass scan, 2-wide) ----------------
__global__ __launch_bounds__(256) void ctx_carry_k(const float* __restrict__ x,
                                                   const float* __restrict__ tau_ctx,
                                                   float* __restrict__ car){
  int gid = blockIdx.x*256 + threadIdx.x;       // B*NC*E/2 = 65536
  int e2 = (gid & 511)*2, bc = gid >> 9;
  int b = bc >> 5, chunk = bc & 31;
  float alpha = 1.f/(1.f+expf(tau_ctx[0]));
  const float2* xp = (const float2*)(x + ((size_t)b*T_DIM + chunk*CL)*E_DIM + e2);
  float h0 = 0.f, h1 = 0.f;
  #pragma unroll 8
  for (int t = 0; t < CL; t++){
    float2 v = xp[(size_t)t*512];
    h0 = alpha*h0 + v.x; h1 = alpha*h1 + v.y;
  }
  *(float2*)&car[(size_t)bc*E_DIM + e2] = make_float2(h0, h1);
}

// writes BOTH halves of gatein: cols [0,1024) = bf16(x), [1024,2048) = bf16(ctx)
__global__ __launch_bounds__(256) void ctx_scan_k(const float* __restrict__ x,
                                                  const float* __restrict__ tau_ctx,
                                                  const float* __restrict__ car,
                                                  unsigned short* __restrict__ gatein){
  int gid = blockIdx.x*256 + threadIdx.x;
  int e2 = (gid & 511)*2, bc = gid >> 9;
  int b = bc >> 5, chunk = bc & 31;
  float alpha = 1.f/(1.f+expf(tau_ctx[0]));
  float alphaL = powf(alpha, (float)CL);
  float h0 = 0.f, h1 = 0.f;
  for (int j = 0; j < chunk; j++){
    float2 c = *(const float2*)&car[(size_t)(b*NC + j)*E_DIM + e2];
    h0 = alphaL*h0 + c.x; h1 = alphaL*h1 + c.y;
  }
  const float2* xp = (const float2*)(x + ((size_t)b*T_DIM + chunk*CL)*E_DIM + e2);
  unsigned int* op = (unsigned int*)(gatein + ((size_t)(b*T_DIM + chunk*CL))*2048 + e2);
  #pragma unroll 4
  for (int t = 0; t < CL; t++){
    float2 v = xp[(size_t)t*512];
    h0 = alpha*h0 + v.x; h1 = alpha*h1 + v.y;
    op[(size_t)t*1024]       = pack2(v.x, v.y);   // x half
    op[(size_t)t*1024 + 512] = pack2(h0, h1);     // ctx half
  }
}

// ---------------- dendrite EMAs (chunked 2-pass, 2-wide), fused blend ----------------
__global__ __launch_bounds__(256) void dend_carry_k(const unsigned short* __restrict__ gated,
                                                    const float* __restrict__ mod,
                                                    const float* __restrict__ tau_raws,
                                                    float* __restrict__ car){
  int gid = blockIdx.x*256 + threadIdx.x;
  int e2 = (gid & 511)*2, bc = gid >> 9;
  int b = bc >> 5, chunk = bc & 31;
  float a[4];
  #pragma unroll
  for (int d = 0; d < 4; d++) a[d] = 1.f/(1.f+expf(tau_raws[d]));
  const ushort2* gp = (const ushort2*)(gated + ((size_t)(b*T_DIM + chunk*CL))*E_DIM + e2);
  const float4* mp = (const float4*)(mod + (size_t)(b*T_DIM + chunk*CL)*4);
  float hx[4] = {0,0,0,0}, hy[4] = {0,0,0,0};
  #pragma unroll 4
  for (int t = 0; t < CL; t++){
    ushort2 gv = gp[(size_t)t*512];
    float gx = bf2f(gv.x), gy = bf2f(gv.y);
    float4 m4 = mp[t];
    hx[0] = a[0]*hx[0] + gx*m4.x; hy[0] = a[0]*hy[0] + gy*m4.x;
    hx[1] = a[1]*hx[1] + gx*m4.y; hy[1] = a[1]*hy[1] + gy*m4.y;
    hx[2] = a[2]*hx[2] + gx*m4.z; hy[2] = a[2]*hy[2] + gy*m4.z;
    hx[3] = a[3]*hx[3] + gx*m4.w; hy[3] = a[3]*hy[3] + gy*m4.w;
  }
  #pragma unroll
  for (int d = 0; d < 4; d++)
    *(float2*)&car[(size_t)d*131072 + (size_t)bc*E_DIM + e2] = make_float2(hx[d], hy[d]);
}

__global__ __launch_bounds__(256) void dend_scan_k(const unsigned short* __restrict__ gated,
                                                   const float* __restrict__ mod,
                                                   const float* __restrict__ tau_raws,
                                                   const float* __restrict__ car,
                                                   const float* __restrict__ blend,
                                                   unsigned short* __restrict__ temporal){
  int gid = blockIdx.x*256 + threadIdx.x;
  int e2 = (gid & 511)*2, bc = gid >> 9;
  int b = bc >> 5, chunk = bc & 31;
  float a[4], hx[4], hy[4];
  #pragma unroll
  for (int d = 0; d < 4; d++) a[d] = 1.f/(1.f+expf(tau_raws[d]));
  #pragma unroll
  for (int d = 0; d < 4; d++){
    float aL = powf(a[d], (float)CL);
    float h0 = 0.f, h1 = 0.f;
    for (int j = 0; j < chunk; j++){
      float2 c = *(const float2*)&car[(size_t)d*131072 + (size_t)(b*NC + j)*E_DIM + e2];
      h0 = aL*h0 + c.x; h1 = aL*h1 + c.y;
    }
    hx[d] = h0; hy[d] = h1;
  }
  float blx[4], bly[4];
  #pragma unroll
  for (int d = 0; d < 4; d++){
    float2 bl = *(const float2*)&blend[(size_t)d*E_DIM + e2];
    blx[d] = bl.x; bly[d] = bl.y;
  }
  float mxx = fmaxf(fmaxf(blx[0],blx[1]), fmaxf(blx[2],blx[3]));
  float mxy = fmaxf(fmaxf(bly[0],bly[1]), fmaxf(bly[2],bly[3]));
  float wx[4], wy[4], sx = 0.f, sy = 0.f;
  #pragma unroll
  for (int d = 0; d < 4; d++){ wx[d] = __expf(blx[d]-mxx); sx += wx[d];
                               wy[d] = __expf(bly[d]-mxy); sy += wy[d]; }
  float ix = 1.f/sx, iy = 1.f/sy;
  #pragma unroll
  for (int d = 0; d < 4; d++){ wx[d] *= ix; wy[d] *= iy; }

  const ushort2* gp = (const ushort2*)(gated + ((size_t)(b*T_DIM + chunk*CL))*E_DIM + e2);
  const float4* mp = (const float4*)(mod + (size_t)(b*T_DIM + chunk*CL)*4);
  unsigned int* op = (unsigned int*)(temporal + ((size_t)(b*T_DIM + chunk*CL))*E_DIM + e2);
  #pragma unroll 4
  for (int t = 0; t < CL; t++){
    ushort2 gv = gp[(size_t)t*512];
    float gx = bf2f(gv.x), gy = bf2f(gv.y);
    float4 m4 = mp[t];
    hx[0] = a[0]*hx[0] + gx*m4.x; hy[0] = a[0]*hy[0] + gy*m4.x;
    hx[1] = a[1]*hx[1] + gx*m4.y; hy[1] = a[1]*hy[1] + gy*m4.y;
    hx[2] = a[2]*hx[2] + gx*m4.z; hy[2] = a[2]*hy[2] + gy*m4.z;
    hx[3] = a[3]*hx[3] + gx*m4.w; hy[3] = a[3]*hy[3] + gy*m4.w;
    float tvx = wx[0]*hx[0] + wx[1]*hx[1] + wx[2]*hx[2] + wx[3]*hx[3];
    float tvy = wy[0]*hy[0] + wy[1]*hy[1] + wy[2]*hy[2] + wy[3]*hy[3];
    op[(size_t)t*512] = pack2(tvx, tvy);
  }
}

// ---------------- mod = 0.5 + sigmoid(h1 @ Wn2^T + bn2) ----------------
__global__ __launch_bounds__(256) void mod_k(const unsigned short* __restrict__ h1,
                                             const float* __restrict__ Wn2,
                                             const float* __restrict__ bn2,
                                             float* __restrict__ mod){
  int wave = threadIdx.x >> 6, lane = threadIdx.x & 63;
  int m = blockIdx.x*4 + wave;
  float p0=0.f,p1=0.f,p2=0.f,p3=0.f;
  for (int c = lane; c < 256; c += 64){
    float h = bf2f(h1[(size_t)m*256 + c]);
    p0 += h*Wn2[0*256 + c]; p1 += h*Wn2[1*256 + c];
    p2 += h*Wn2[2*256 + c]; p3 += h*Wn2[3*256 + c];
  }
  #pragma unroll
  for (int off = 32; off > 0; off >>= 1){
    p0 += __shfl_down(p0, off); p1 += __shfl_down(p1, off);
    p2 += __shfl_down(p2, off); p3 += __shfl_down(p3, off);
  }
  if (lane == 0){
    mod[(size_t)m*4 + 0] = 0.5f + sigf(p0 + bn2[0]);
    mod[(size_t)m*4 + 1] = 0.5f + sigf(p1 + bn2[1]);
    mod[(size_t)m*4 + 2] = 0.5f + sigf(p2 + bn2[2]);
    mod[(size_t)m*4 + 3] = 0.5f + sigf(p3 + bn2[3]);
  }
}

// ---------------- bf16 MFMA GEMM with global_load_lds staging ----------------
// out[m,n] = sum_k A[m,k]*W[n,k]
// EPI: 0 = gated = x*sigmoid(v+bias) -> bf16
//      1 = dual gelu: col<1024 -> outp (stride 1024), else -> outp2 (stride 256)
//      2 = sg = sigmoid(v+bias)*ebf -> bf16
//      3 = plain f32
template<int EPI>
__global__ __launch_bounds__(256, 2) void gemm_k(
    const unsigned short* __restrict__ A, int lda,
    const unsigned short* __restrict__ Bw, int K,
    const float* __restrict__ bias,
    const float* __restrict__ xf32,
    const unsigned short* __restrict__ ebf,
    void* __restrict__ outp, void* __restrict__ outp2)
{
  __shared__ unsigned short sA[128*32];
  __shared__ unsigned short sB[128*32];
  const int tid = threadIdx.x;
  const int wv = tid >> 6, lane = tid & 63;
  const int quad = lane >> 4, l15 = lane & 15;
  const int wm = (wv & 1) * 64, wn = (wv >> 1) * 64;
  const int row0 = blockIdx.x * 128, col0 = blockIdx.y * 128;

  const int r = tid >> 2, kc = (tid & 3) * 8;
  const unsigned short* pa0 = A  + (size_t)(row0 + r)*lda      + kc;
  const unsigned short* pa1 = A  + (size_t)(row0 + 64 + r)*lda + kc;
  const unsigned short* pb0 = Bw + (size_t)(col0 + r)*K        + kc;
  const unsigned short* pb1 = Bw + (size_t)(col0 + 64 + r)*K   + kc;
  unsigned short* la0 = &sA[wv*512];
  unsigned short* la1 = &sA[2048 + wv*512];
  unsigned short* lb0 = &sB[wv*512];
  unsigned short* lb1 = &sB[2048 + wv*512];

  f32x4 acc[4][4];
  #pragma unroll
  for (int i = 0; i < 4; i++)
    #pragma unroll
    for (int j = 0; j < 4; j++) acc[i][j] = (f32x4){0.f,0.f,0.f,0.f};

  for (int k0 = 0; k0 < K; k0 += 32){
    __syncthreads();
    glds16(pa0 + k0, la0);
    glds16(pa1 + k0, la1);
    glds16(pb0 + k0, lb0);
    glds16(pb1 + k0, lb1);
    __syncthreads();
    short8 afr[4], bfr[4];
    #pragma unroll
    for (int i = 0; i < 4; i++) afr[i] = *(const short8*)&sA[(wm + i*16 + l15)*32 + quad*8];
    #pragma unroll
    for (int j = 0; j < 4; j++) bfr[j] = *(const short8*)&sB[(wn + j*16 + l15)*32 + quad*8];
    #pragma unroll
    for (int i = 0; i < 4; i++)
      #pragma unroll
      for (int j = 0; j < 4; j++)
        acc[i][j] = __builtin_amdgcn_mfma_f32_16x16x32_bf16(afr[i], bfr[j], acc[i][j], 0, 0, 0);
  }

  #pragma unroll
  for (int i = 0; i < 4; i++){
    #pragma unroll
    for (int j = 0; j < 4; j++){
      const int col = col0 + wn + j*16 + l15;
      #pragma unroll
      for (int rr = 0; rr < 4; rr++){
        const int row = row0 + wm + i*16 + quad*4 + rr;
        float v = acc[i][j][rr];
        if (EPI == 0){
          size_t o = (size_t)row*1024 + col;
          v += bias[col];
          ((unsigned short*)outp)[o] = f2bf(xf32[o] * sigf(v));
        } else if (EPI == 1){
          v += bias[col];
          float g = geluf(v);
          if (col < 1024) ((unsigned short*)outp )[(size_t)row*1024 + col]        = f2bf(g);
          else            ((unsigned short*)outp2)[(size_t)row*256  + (col-1024)] = f2bf(g);
        } else if (EPI == 2){
          size_t o = (size_t)row*1024 + col;
          v += bias[col];
          ((unsigned short*)outp)[o] = f2bf(sigf(v) * bf2f(ebf[o]));
        } else {
          ((float*)outp)[(size_t)row*1024 + col] = v;
        }
      }
    }
  }
}

// ---------------- LayerNorm over E=1024 ----------------
__global__ __launch_bounds__(256) void ln_k(const float* __restrict__ in,
                                            const float* __restrict__ gamma,
                                            const float* __restrict__ beta,
                                            float* __restrict__ out){
  __shared__ float s1[4], s2[4];
  int row = blockIdx.x, tid = threadIdx.x;
  float4 v = *(const float4*)&in[(size_t)row*1024 + tid*4];
  float s = v.x+v.y+v.z+v.w;
  float q = v.x*v.x+v.y*v.y+v.z*v.z+v.w*v.w;
  #pragma unroll
  for (int off = 32; off > 0; off >>= 1){ s += __shfl_down(s, off); q += __shfl_down(q, off); }
  int wave = tid >> 6, lane = tid & 63;
  if (lane == 0){ s1[wave] = s; s2[wave] = q; }
  __syncthreads();
  s = s1[0]+s1[1]+s1[2]+s1[3];
  q = s2[0]+s2[1]+s2[2]+s2[3];
  float mu = s*(1.f/1024.f);
  float var = q*(1.f/1024.f) - mu*mu;
  float rs = rsqrtf(var + 1e-5f);
  int c = tid*4;
  float4 g = *(const float4*)&gamma[c];
  float4 bb = *(const float4*)&beta[c];
  float4 o;
  o.x = (v.x-mu)*rs*g.x + bb.x;
  o.y = (v.y-mu)*rs*g.y + bb.y;
  o.z = (v.z-mu)*rs*g.z + bb.z;
  o.w = (v.w-mu)*rs*g.w + bb.w;
  *(float4*)&out[(size_t)row*1024 + c] = o;
}

// ---------------- launch ----------------
extern "C" void kernel_launch(void* const* d_in, const int* in_sizes, int n_in,
                              void* d_out, int out_size, void* d_ws, size_t ws_size,
                              hipStream_t stream) {
  const float* x        = (const float*)d_in[0];
  const float* tau_ctx  = (const float*)d_in[1];
  const float* tau_raws = (const float*)d_in[2];
  const float* Wg       = (const float*)d_in[3];
  const float* bg       = (const float*)d_in[4];
  const float* Wn1      = (const float*)d_in[5];
  const float* bn1      = (const float*)d_in[6];
  const float* Wn2      = (const float*)d_in[7];
  const float* bn2      = (const float*)d_in[8];
  const float* blend    = (const float*)d_in[9];
  const float* Wsoma    = (const float*)d_in[10];
  const float* bsoma    = (const float*)d_in[11];
  const float* Wtemp    = (const float*)d_in[12];
  const float* btemp    = (const float*)d_in[13];
  const float* Wout     = (const float*)d_in[14];
  const float* gamma    = (const float*)d_in[15];
  const float* beta     = (const float*)d_in[16];

  char* ws = (char*)d_ws;
  // workspace layout (bytes); aliases annotated
  unsigned short* gatein   = (unsigned short*)(ws + 0);          // M x 2048 bf16, dead after step 4
  float*          out_pre  = (float*)(ws + 0);                   // alias of gatein (step 9+)
  unsigned short* wg_bf    = (unsigned short*)(ws + 33554432);   // 1024 x 2048 bf16
  unsigned short* wsn1     = (unsigned short*)(ws + 37748736);   // 1280 x 1024 bf16 (Wsoma rows 0..1023, Wn1 rows 1024..1279)
  unsigned short* wtemp_bf = (unsigned short*)(ws + 40370176);   // 1024 x 1024 bf16
  unsigned short* wout_bf  = (unsigned short*)(ws + 42467328);   // 1024 x 1024 bf16
  float*          bsn1     = (float*)(ws + 44564480);            // 1280 f32 (bsoma | bn1)
  unsigned short* h1_bf    = (unsigned short*)(ws + 44572672);   // M x 256 bf16, dead after mod_k
  float*          car_d    = (float*)(ws + 44572672);            // alias of h1_bf: 4 x B*NC*E f32 (2MB)
  float*          car_ctx  = (float*)(ws + 48766976);            // B*NC*E f32 (512KB), dead after ctx_scan
  float*          modbuf   = (float*)(ws + 48766976);            // alias of car_ctx: M x 4 f32
  unsigned short* gated    = (unsigned short*)(ws + 49291264);   // M x 1024 bf16
  unsigned short* sg       = gated;                              // alias (gated dead after dend scans)
  unsigned short* temporal = (unsigned short*)(ws + 66068480);   // M x 1024 bf16
  unsigned short* soma     = (unsigned short*)(ws + 82845696);   // M x 1024 bf16

  // 1) all weight/bias converts in one launch
  conv_all_k<<<dim3(5378), dim3(256), 0, stream>>>(Wg, Wsoma, Wn1, Wtemp, Wout, bsoma, bn1,
                                                   wg_bf, wsn1, wtemp_bf, wout_bf, bsn1);

  // 2-3) ctx EMA; scan also writes the x-half of gatein
  ctx_carry_k<<<dim3(256), dim3(256), 0, stream>>>(x, tau_ctx, car_ctx);
  ctx_scan_k <<<dim3(256), dim3(256), 0, stream>>>(x, tau_ctx, car_ctx, gatein);

  // 4) gate GEMM: gated = x * sigmoid(gatein@Wg^T + bg)
  gemm_k<0><<<dim3(64, 8), dim3(256), 0, stream>>>(
      gatein, 2048, wg_bf, 2048, bg, x, nullptr, gated, nullptr);

  // 5) combined soma|h1 GEMM: gelu(x@[Wsoma;Wn1]^T + [bsoma;bn1])
  gemm_k<1><<<dim3(64, 10), dim3(256), 0, stream>>>(
      gatein, 2048, wsn1, 1024, bsn1, nullptr, nullptr, soma, h1_bf);

  // 6) mod
  mod_k<<<dim3(M_ROWS/4), dim3(256), 0, stream>>>(h1_bf, Wn2, bn2, modbuf);

  // 7-8) dendrite EMAs -> temporal (car_d overwrites h1_bf, now dead)
  dend_carry_k<<<dim3(256), dim3(256), 0, stream>>>(gated, modbuf, tau_raws, car_d);
  dend_scan_k <<<dim3(256), dim3(256), 0, stream>>>(gated, modbuf, tau_raws, car_d, blend, temporal);

  // 9) sg = soma * sigmoid(temporal@Wtemp^T + btemp)  (overwrites gated)
  gemm_k<2><<<dim3(64, 8), dim3(256), 0, stream>>>(
      temporal, 1024, wtemp_bf, 1024, btemp, nullptr, soma, sg, nullptr);

  // 10) out_pre = sg@Wout^T  (overwrites gatein)
  gemm_k<3><<<dim3(64, 8), dim3(256), 0, stream>>>(
      sg, 1024, wout_bf, 1024, nullptr, nullptr, nullptr, out_pre, nullptr);

  // 11) LayerNorm
  ln_k<<<dim3(M_ROWS), dim3(256), 0, stream>>>(out_pre, gamma, beta, (float*)d_out);
}

// Round 3
// 342.830 us; speedup vs baseline: 1.1388x; 1.1289x over previous
//
#include <hip/hip_runtime.h>
#include <math.h>

#define B_DIM 4
#define T_DIM 2048
#define E_DIM 1024
#define M_ROWS (B_DIM*T_DIM)   /* 8192 */
#define NC 32                  /* scan chunks per sequence */
#define CL (T_DIM/NC)          /* 64 */

typedef short short8 __attribute__((ext_vector_type(8)));
typedef float f32x4 __attribute__((ext_vector_type(4)));

__device__ __forceinline__ float bf2f(unsigned short u){
  union { unsigned int i; float f; } c; c.i = ((unsigned int)u) << 16; return c.f;
}
__device__ __forceinline__ unsigned short f2bf(float f){
  union { float f; unsigned int i; } c; c.f = f;
  unsigned int u = c.i;
  return (unsigned short)((u + 0x7FFFu + ((u >> 16) & 1u)) >> 16);
}
__device__ __forceinline__ unsigned int pack2(float a, float b){
  return (unsigned int)f2bf(a) | ((unsigned int)f2bf(b) << 16);
}
__device__ __forceinline__ float sigf(float x){ return 1.f/(1.f+__expf(-x)); }
__device__ __forceinline__ float geluf(float x){ return 0.5f*x*(1.f+erff(x*0.70710678118f)); }

__device__ __forceinline__ void glds16(const unsigned short* g, unsigned short* l){
  __builtin_amdgcn_global_load_lds((const __attribute__((address_space(1))) void*)g,
                                   (__attribute__((address_space(3))) void*)l, 16, 0, 0);
}

// ---------------- fused weight/bias converts ----------------
__device__ __forceinline__ void cvt4(const float* __restrict__ s, unsigned short* __restrict__ d){
  float4 v = *(const float4*)s;
  uint2 p; p.x = pack2(v.x, v.y); p.y = pack2(v.z, v.w);
  *(uint2*)d = p;
}

__global__ __launch_bounds__(256) void conv_all_k(
    const float* __restrict__ Wg, const float* __restrict__ Wsoma,
    const float* __restrict__ Wn1, const float* __restrict__ Wtemp,
    const float* __restrict__ Wout, const float* __restrict__ bsoma,
    const float* __restrict__ bn1,
    unsigned short* __restrict__ wg_bf, unsigned short* __restrict__ wsn1,
    unsigned short* __restrict__ wtemp_bf, unsigned short* __restrict__ wout_bf,
    float* __restrict__ bsn1){
  int u = blockIdx.x*256 + threadIdx.x;
  if (u < 524288){ cvt4(Wg + (size_t)u*4, wg_bf + (size_t)u*4); }
  else if (u < 786432){ u -= 524288; cvt4(Wsoma + (size_t)u*4, wsn1 + (size_t)u*4); }
  else if (u < 851968){ u -= 786432; cvt4(Wn1 + (size_t)u*4, wsn1 + 1048576 + (size_t)u*4); }
  else if (u < 1114112){ u -= 851968; cvt4(Wtemp + (size_t)u*4, wtemp_bf + (size_t)u*4); }
  else if (u < 1376256){ u -= 1114112; cvt4(Wout + (size_t)u*4, wout_bf + (size_t)u*4); }
  else if (u < 1376576){
    u -= 1376256; int i = u*4;
    float4 v = (i < 1024) ? *(const float4*)&bsoma[i] : *(const float4*)&bn1[i-1024];
    *(float4*)&bsn1[i] = v;
  }
}

// ---------------- ctx EMA (chunked 2-pass scan, 2-wide) ----------------
__global__ __launch_bounds__(256) void ctx_carry_k(const float* __restrict__ x,
                                                   const float* __restrict__ tau_ctx,
                                                   float* __restrict__ car){
  int gid = blockIdx.x*256 + threadIdx.x;       // B*NC*E/2 = 65536
  int e2 = (gid & 511)*2, bc = gid >> 9;
  int b = bc >> 5, chunk = bc & 31;
  float alpha = 1.f/(1.f+expf(tau_ctx[0]));
  const float2* xp = (const float2*)(x + ((size_t)b*T_DIM + chunk*CL)*E_DIM + e2);
  float h0 = 0.f, h1 = 0.f;
  #pragma unroll 8
  for (int t = 0; t < CL; t++){
    float2 v = xp[(size_t)t*512];
    h0 = alpha*h0 + v.x; h1 = alpha*h1 + v.y;
  }
  *(float2*)&car[(size_t)bc*E_DIM + e2] = make_float2(h0, h1);
}

// writes BOTH halves of gatein: cols [0,1024) = bf16(x), [1024,2048) = bf16(ctx)
__global__ __launch_bounds__(256) void ctx_scan_k(const float* __restrict__ x,
                                                  const float* __restrict__ tau_ctx,
                                                  const float* __restrict__ car,
                                                  unsigned short* __restrict__ gatein){
  int gid = blockIdx.x*256 + threadIdx.x;
  int e2 = (gid & 511)*2, bc = gid >> 9;
  int b = bc >> 5, chunk = bc & 31;
  float alpha = 1.f/(1.f+expf(tau_ctx[0]));
  float alphaL = powf(alpha, (float)CL);
  float h0 = 0.f, h1 = 0.f;
  for (int j = 0; j < chunk; j++){
    float2 c = *(const float2*)&car[(size_t)(b*NC + j)*E_DIM + e2];
    h0 = alphaL*h0 + c.x; h1 = alphaL*h1 + c.y;
  }
  const float2* xp = (const float2*)(x + ((size_t)b*T_DIM + chunk*CL)*E_DIM + e2);
  unsigned int* op = (unsigned int*)(gatein + ((size_t)(b*T_DIM + chunk*CL))*2048 + e2);
  #pragma unroll 4
  for (int t = 0; t < CL; t++){
    float2 v = xp[(size_t)t*512];
    h0 = alpha*h0 + v.x; h1 = alpha*h1 + v.y;
    op[(size_t)t*1024]       = pack2(v.x, v.y);   // x half
    op[(size_t)t*1024 + 512] = pack2(h0, h1);     // ctx half
  }
}

// ---------------- dendrite EMAs (chunked 2-pass, 2-wide), fused blend ----------------
__global__ __launch_bounds__(256) void dend_carry_k(const unsigned short* __restrict__ gated,
                                                    const float* __restrict__ mod,
                                                    const float* __restrict__ tau_raws,
                                                    float* __restrict__ car){
  int gid = blockIdx.x*256 + threadIdx.x;
  int e2 = (gid & 511)*2, bc = gid >> 9;
  int b = bc >> 5, chunk = bc & 31;
  float a[4];
  #pragma unroll
  for (int d = 0; d < 4; d++) a[d] = 1.f/(1.f+expf(tau_raws[d]));
  const ushort2* gp = (const ushort2*)(gated + ((size_t)(b*T_DIM + chunk*CL))*E_DIM + e2);
  const float4* mp = (const float4*)(mod + (size_t)(b*T_DIM + chunk*CL)*4);
  float hx[4] = {0,0,0,0}, hy[4] = {0,0,0,0};
  #pragma unroll 4
  for (int t = 0; t < CL; t++){
    ushort2 gv = gp[(size_t)t*512];
    float gx = bf2f(gv.x), gy = bf2f(gv.y);
    float4 m4 = mp[t];
    hx[0] = a[0]*hx[0] + gx*m4.x; hy[0] = a[0]*hy[0] + gy*m4.x;
    hx[1] = a[1]*hx[1] + gx*m4.y; hy[1] = a[1]*hy[1] + gy*m4.y;
    hx[2] = a[2]*hx[2] + gx*m4.z; hy[2] = a[2]*hy[2] + gy*m4.z;
    hx[3] = a[3]*hx[3] + gx*m4.w; hy[3] = a[3]*hy[3] + gy*m4.w;
  }
  #pragma unroll
  for (int d = 0; d < 4; d++)
    *(float2*)&car[(size_t)d*131072 + (size_t)bc*E_DIM + e2] = make_float2(hx[d], hy[d]);
}

__global__ __launch_bounds__(256) void dend_scan_k(const unsigned short* __restrict__ gated,
                                                   const float* __restrict__ mod,
                                                   const float* __restrict__ tau_raws,
                                                   const float* __restrict__ car,
                                                   const float* __restrict__ blend,
                                                   unsigned short* __restrict__ temporal){
  int gid = blockIdx.x*256 + threadIdx.x;
  int e2 = (gid & 511)*2, bc = gid >> 9;
  int b = bc >> 5, chunk = bc & 31;
  float a[4], hx[4], hy[4];
  #pragma unroll
  for (int d = 0; d < 4; d++) a[d] = 1.f/(1.f+expf(tau_raws[d]));
  #pragma unroll
  for (int d = 0; d < 4; d++){
    float aL = powf(a[d], (float)CL);
    float h0 = 0.f, h1 = 0.f;
    for (int j = 0; j < chunk; j++){
      float2 c = *(const float2*)&car[(size_t)d*131072 + (size_t)(b*NC + j)*E_DIM + e2];
      h0 = aL*h0 + c.x; h1 = aL*h1 + c.y;
    }
    hx[d] = h0; hy[d] = h1;
  }
  float blx[4], bly[4];
  #pragma unroll
  for (int d = 0; d < 4; d++){
    float2 bl = *(const float2*)&blend[(size_t)d*E_DIM + e2];
    blx[d] = bl.x; bly[d] = bl.y;
  }
  float mxx = fmaxf(fmaxf(blx[0],blx[1]), fmaxf(blx[2],blx[3]));
  float mxy = fmaxf(fmaxf(bly[0],bly[1]), fmaxf(bly[2],bly[3]));
  float wx[4], wy[4], sx = 0.f, sy = 0.f;
  #pragma unroll
  for (int d = 0; d < 4; d++){ wx[d] = __expf(blx[d]-mxx); sx += wx[d];
                               wy[d] = __expf(bly[d]-mxy); sy += wy[d]; }
  float ix = 1.f/sx, iy = 1.f/sy;
  #pragma unroll
  for (int d = 0; d < 4; d++){ wx[d] *= ix; wy[d] *= iy; }

  const ushort2* gp = (const ushort2*)(gated + ((size_t)(b*T_DIM + chunk*CL))*E_DIM + e2);
  const float4* mp = (const float4*)(mod + (size_t)(b*T_DIM + chunk*CL)*4);
  unsigned int* op = (unsigned int*)(temporal + ((size_t)(b*T_DIM + chunk*CL))*E_DIM + e2);
  #pragma unroll 4
  for (int t = 0; t < CL; t++){
    ushort2 gv = gp[(size_t)t*512];
    float gx = bf2f(gv.x), gy = bf2f(gv.y);
    float4 m4 = mp[t];
    hx[0] = a[0]*hx[0] + gx*m4.x; hy[0] = a[0]*hy[0] + gy*m4.x;
    hx[1] = a[1]*hx[1] + gx*m4.y; hy[1] = a[1]*hy[1] + gy*m4.y;
    hx[2] = a[2]*hx[2] + gx*m4.z; hy[2] = a[2]*hy[2] + gy*m4.z;
    hx[3] = a[3]*hx[3] + gx*m4.w; hy[3] = a[3]*hy[3] + gy*m4.w;
    float tvx = wx[0]*hx[0] + wx[1]*hx[1] + wx[2]*hx[2] + wx[3]*hx[3];
    float tvy = wy[0]*hy[0] + wy[1]*hy[1] + wy[2]*hy[2] + wy[3]*hy[3];
    op[(size_t)t*512] = pack2(tvx, tvy);
  }
}

// ---------------- mod = 0.5 + sigmoid(h1 @ Wn2^T + bn2) ----------------
__global__ __launch_bounds__(256) void mod_k(const unsigned short* __restrict__ h1,
                                             const float* __restrict__ Wn2,
                                             const float* __restrict__ bn2,
                                             float* __restrict__ mod){
  int wave = threadIdx.x >> 6, lane = threadIdx.x & 63;
  int m = blockIdx.x*4 + wave;
  float p0=0.f,p1=0.f,p2=0.f,p3=0.f;
  for (int c = lane; c < 256; c += 64){
    float h = bf2f(h1[(size_t)m*256 + c]);
    p0 += h*Wn2[0*256 + c]; p1 += h*Wn2[1*256 + c];
    p2 += h*Wn2[2*256 + c]; p3 += h*Wn2[3*256 + c];
  }
  #pragma unroll
  for (int off = 32; off > 0; off >>= 1){
    p0 += __shfl_down(p0, off); p1 += __shfl_down(p1, off);
    p2 += __shfl_down(p2, off); p3 += __shfl_down(p3, off);
  }
  if (lane == 0){
    mod[(size_t)m*4 + 0] = 0.5f + sigf(p0 + bn2[0]);
    mod[(size_t)m*4 + 1] = 0.5f + sigf(p1 + bn2[1]);
    mod[(size_t)m*4 + 2] = 0.5f + sigf(p2 + bn2[2]);
    mod[(size_t)m*4 + 3] = 0.5f + sigf(p3 + bn2[3]);
  }
}

// ============ fused GEMM1: gate | soma | h1, double-buffered glds prefetch ========
// by<8:  gated = bf16(x)*sigmoid(gatein@Wg^T+bg), K=2048
// 8..15: soma  = gelu(x@Wsoma^T+bsoma),           K=1024
// 16,17: h1    = gelu(x@Wn1^T+bn1),               K=1024
__global__ __launch_bounds__(256, 2) void gemm1_k(
    const unsigned short* __restrict__ gatein,
    const unsigned short* __restrict__ wg_bf,
    const unsigned short* __restrict__ wsn1,
    const float* __restrict__ bg,
    const float* __restrict__ bsn1,
    unsigned short* __restrict__ gated,
    unsigned short* __restrict__ soma,
    unsigned short* __restrict__ h1)
{
  __shared__ unsigned short sA[2][4096];
  __shared__ unsigned short sB[2][4096];
  const int tid = threadIdx.x;
  const int wv = tid >> 6, lane = tid & 63;
  const int quad = lane >> 4, l15 = lane & 15;
  const int wm = (wv & 1) * 64, wn = (wv >> 1) * 64;
  const int row0 = blockIdx.x * 128;
  const int by = blockIdx.y;

  int mode, colw0, K;
  const unsigned short* Bw;
  const float* bias;
  if (by < 8)       { mode = 0; colw0 = by*128;            Bw = wg_bf + (size_t)colw0*2048; K = 2048; bias = bg   + colw0; }
  else if (by < 16) { mode = 1; colw0 = (by-8)*128;        Bw = wsn1  + (size_t)colw0*1024; K = 1024; bias = bsn1 + colw0; }
  else              { mode = 2; colw0 = 1024 + (by-16)*128; Bw = wsn1 + (size_t)colw0*1024; K = 1024; bias = bsn1 + colw0; }

  const int r = tid >> 2, kc = (tid & 3) * 8;
  const unsigned short* pa0 = gatein + (size_t)(row0 + r)*2048      + kc;
  const unsigned short* pa1 = gatein + (size_t)(row0 + 64 + r)*2048 + kc;
  const unsigned short* pb0 = Bw + (size_t)r*K        + kc;
  const unsigned short* pb1 = Bw + (size_t)(64 + r)*K + kc;

  f32x4 acc[4][4];
  #pragma unroll
  for (int i = 0; i < 4; i++)
    #pragma unroll
    for (int j = 0; j < 4; j++) acc[i][j] = (f32x4){0.f,0.f,0.f,0.f};

  // prologue: stage tile 0 into buf 0
  glds16(pa0, &sA[0][wv*512]);
  glds16(pa1, &sA[0][2048 + wv*512]);
  glds16(pb0, &sB[0][wv*512]);
  glds16(pb1, &sB[0][2048 + wv*512]);

  const int nk = K >> 5;
  for (int it = 0; it < nk; it++){
    __syncthreads();                 // drains vmcnt: buf[it&1] now valid; buf[1-it&1] free
    const int cur = it & 1, nxt = cur ^ 1;
    if (it + 1 < nk){
      const int ko = (it + 1) << 5;
      glds16(pa0 + ko, &sA[nxt][wv*512]);
      glds16(pa1 + ko, &sA[nxt][2048 + wv*512]);
      glds16(pb0 + ko, &sB[nxt][wv*512]);
      glds16(pb1 + ko, &sB[nxt][2048 + wv*512]);
    }
    short8 afr[4], bfr[4];
    #pragma unroll
    for (int i = 0; i < 4; i++) afr[i] = *(const short8*)&sA[cur][(wm + i*16 + l15)*32 + quad*8];
    #pragma unroll
    for (int j = 0; j < 4; j++) bfr[j] = *(const short8*)&sB[cur][(wn + j*16 + l15)*32 + quad*8];
    #pragma unroll
    for (int i = 0; i < 4; i++)
      #pragma unroll
      for (int j = 0; j < 4; j++)
        acc[i][j] = __builtin_amdgcn_mfma_f32_16x16x32_bf16(afr[i], bfr[j], acc[i][j], 0, 0, 0);
  }

  if (mode == 0){
    #pragma unroll
    for (int i = 0; i < 4; i++)
      #pragma unroll
      for (int j = 0; j < 4; j++){
        const int lc = wn + j*16 + l15;
        const int col = colw0 + lc;
        #pragma unroll
        for (int rr = 0; rr < 4; rr++){
          const int row = row0 + wm + i*16 + quad*4 + rr;
          float v = acc[i][j][rr] + bias[lc];
          float xv = bf2f(gatein[(size_t)row*2048 + col]);
          gated[(size_t)row*1024 + col] = f2bf(xv * sigf(v));
        }
      }
  } else if (mode == 1){
    #pragma unroll
    for (int i = 0; i < 4; i++)
      #pragma unroll
      for (int j = 0; j < 4; j++){
        const int lc = wn + j*16 + l15;
        const int col = colw0 + lc;
        #pragma unroll
        for (int rr = 0; rr < 4; rr++){
          const int row = row0 + wm + i*16 + quad*4 + rr;
          float v = acc[i][j][rr] + bias[lc];
          soma[(size_t)row*1024 + col] = f2bf(geluf(v));
        }
      }
  } else {
    #pragma unroll
    for (int i = 0; i < 4; i++)
      #pragma unroll
      for (int j = 0; j < 4; j++){
        const int lc = wn + j*16 + l15;
        const int col = colw0 - 1024 + lc;
        #pragma unroll
        for (int rr = 0; rr < 4; rr++){
          const int row = row0 + wm + i*16 + quad*4 + rr;
          float v = acc[i][j][rr] + bias[lc];
          h1[(size_t)row*256 + col] = f2bf(geluf(v));
        }
      }
  }
}

// ============ GEMM2/3: K=1024, lda=1024, N=1024, dbuf glds prefetch ============
// EPI 2: sg = sigmoid(v+bias)*ebf -> bf16;  EPI 3: plain f32
template<int EPI>
__global__ __launch_bounds__(256, 2) void gemm_k(
    const unsigned short* __restrict__ A,
    const unsigned short* __restrict__ Bw,
    const float* __restrict__ bias,
    const unsigned short* __restrict__ ebf,
    void* __restrict__ outp)
{
  __shared__ unsigned short sA[2][4096];
  __shared__ unsigned short sB[2][4096];
  const int tid = threadIdx.x;
  const int wv = tid >> 6, lane = tid & 63;
  const int quad = lane >> 4, l15 = lane & 15;
  const int wm = (wv & 1) * 64, wn = (wv >> 1) * 64;
  const int row0 = blockIdx.x * 128, col0 = blockIdx.y * 128;

  const int r = tid >> 2, kc = (tid & 3) * 8;
  const unsigned short* pa0 = A  + (size_t)(row0 + r)*1024      + kc;
  const unsigned short* pa1 = A  + (size_t)(row0 + 64 + r)*1024 + kc;
  const unsigned short* pb0 = Bw + (size_t)(col0 + r)*1024      + kc;
  const unsigned short* pb1 = Bw + (size_t)(col0 + 64 + r)*1024 + kc;

  f32x4 acc[4][4];
  #pragma unroll
  for (int i = 0; i < 4; i++)
    #pragma unroll
    for (int j = 0; j < 4; j++) acc[i][j] = (f32x4){0.f,0.f,0.f,0.f};

  glds16(pa0, &sA[0][wv*512]);
  glds16(pa1, &sA[0][2048 + wv*512]);
  glds16(pb0, &sB[0][wv*512]);
  glds16(pb1, &sB[0][2048 + wv*512]);

  for (int it = 0; it < 32; it++){
    __syncthreads();
    const int cur = it & 1, nxt = cur ^ 1;
    if (it + 1 < 32){
      const int ko = (it + 1) << 5;
      glds16(pa0 + ko, &sA[nxt][wv*512]);
      glds16(pa1 + ko, &sA[nxt][2048 + wv*512]);
      glds16(pb0 + ko, &sB[nxt][wv*512]);
      glds16(pb1 + ko, &sB[nxt][2048 + wv*512]);
    }
    short8 afr[4], bfr[4];
    #pragma unroll
    for (int i = 0; i < 4; i++) afr[i] = *(const short8*)&sA[cur][(wm + i*16 + l15)*32 + quad*8];
    #pragma unroll
    for (int j = 0; j < 4; j++) bfr[j] = *(const short8*)&sB[cur][(wn + j*16 + l15)*32 + quad*8];
    #pragma unroll
    for (int i = 0; i < 4; i++)
      #pragma unroll
      for (int j = 0; j < 4; j++)
        acc[i][j] = __builtin_amdgcn_mfma_f32_16x16x32_bf16(afr[i], bfr[j], acc[i][j], 0, 0, 0);
  }

  #pragma unroll
  for (int i = 0; i < 4; i++)
    #pragma unroll
    for (int j = 0; j < 4; j++){
      const int col = col0 + wn + j*16 + l15;
      #pragma unroll
      for (int rr = 0; rr < 4; rr++){
        const int row = row0 + wm + i*16 + quad*4 + rr;
        float v = acc[i][j][rr];
        size_t o = (size_t)row*1024 + col;
        if (EPI == 2){
          v += bias[col];
          ((unsigned short*)outp)[o] = f2bf(sigf(v) * bf2f(ebf[o]));
        } else {
          ((float*)outp)[o] = v;
        }
      }
    }
}

// ---------------- LayerNorm over E=1024 ----------------
__global__ __launch_bounds__(256) void ln_k(const float* __restrict__ in,
                                            const float* __restrict__ gamma,
                                            const float* __restrict__ beta,
                                            float* __restrict__ out){
  __shared__ float s1[4], s2[4];
  int row = blockIdx.x, tid = threadIdx.x;
  float4 v = *(const float4*)&in[(size_t)row*1024 + tid*4];
  float s = v.x+v.y+v.z+v.w;
  float q = v.x*v.x+v.y*v.y+v.z*v.z+v.w*v.w;
  #pragma unroll
  for (int off = 32; off > 0; off >>= 1){ s += __shfl_down(s, off); q += __shfl_down(q, off); }
  int wave = tid >> 6, lane = tid & 63;
  if (lane == 0){ s1[wave] = s; s2[wave] = q; }
  __syncthreads();
  s = s1[0]+s1[1]+s1[2]+s1[3];
  q = s2[0]+s2[1]+s2[2]+s2[3];
  float mu = s*(1.f/1024.f);
  float var = q*(1.f/1024.f) - mu*mu;
  float rs = rsqrtf(var + 1e-5f);
  int c = tid*4;
  float4 g = *(const float4*)&gamma[c];
  float4 bb = *(const float4*)&beta[c];
  float4 o;
  o.x = (v.x-mu)*rs*g.x + bb.x;
  o.y = (v.y-mu)*rs*g.y + bb.y;
  o.z = (v.z-mu)*rs*g.z + bb.z;
  o.w = (v.w-mu)*rs*g.w + bb.w;
  *(float4*)&out[(size_t)row*1024 + c] = o;
}

// ---------------- launch ----------------
extern "C" void kernel_launch(void* const* d_in, const int* in_sizes, int n_in,
                              void* d_out, int out_size, void* d_ws, size_t ws_size,
                              hipStream_t stream) {
  const float* x        = (const float*)d_in[0];
  const float* tau_ctx  = (const float*)d_in[1];
  const float* tau_raws = (const float*)d_in[2];
  const float* Wg       = (const float*)d_in[3];
  const float* bg       = (const float*)d_in[4];
  const float* Wn1      = (const float*)d_in[5];
  const float* bn1      = (const float*)d_in[6];
  const float* Wn2      = (const float*)d_in[7];
  const float* bn2      = (const float*)d_in[8];
  const float* blend    = (const float*)d_in[9];
  const float* Wsoma    = (const float*)d_in[10];
  const float* bsoma    = (const float*)d_in[11];
  const float* Wtemp    = (const float*)d_in[12];
  const float* btemp    = (const float*)d_in[13];
  const float* Wout     = (const float*)d_in[14];
  const float* gamma    = (const float*)d_in[15];
  const float* beta     = (const float*)d_in[16];

  char* ws = (char*)d_ws;
  unsigned short* gatein   = (unsigned short*)(ws + 0);          // M x 2048 bf16, dead after gemm1
  float*          out_pre  = (float*)(ws + 0);                   // alias of gatein
  unsigned short* wg_bf    = (unsigned short*)(ws + 33554432);   // 1024 x 2048 bf16
  unsigned short* wsn1     = (unsigned short*)(ws + 37748736);   // 1280 x 1024 bf16 (Wsoma | Wn1)
  unsigned short* wtemp_bf = (unsigned short*)(ws + 40370176);   // 1024 x 1024 bf16
  unsigned short* wout_bf  = (unsigned short*)(ws + 42467328);   // 1024 x 1024 bf16
  float*          bsn1     = (float*)(ws + 44564480);            // 1280 f32
  unsigned short* h1_bf    = (unsigned short*)(ws + 44572672);   // M x 256 bf16, dead after mod_k
  float*          car_d    = (float*)(ws + 44572672);            // alias of h1_bf (2MB)
  float*          car_ctx  = (float*)(ws + 48766976);            // 512KB, dead after ctx_scan
  float*          modbuf   = (float*)(ws + 48766976);            // alias of car_ctx
  unsigned short* gated    = (unsigned short*)(ws + 49291264);   // M x 1024 bf16
  unsigned short* sg       = gated;                              // alias
  unsigned short* temporal = (unsigned short*)(ws + 66068480);   // M x 1024 bf16
  unsigned short* soma     = (unsigned short*)(ws + 82845696);   // M x 1024 bf16

  conv_all_k<<<dim3(5378), dim3(256), 0, stream>>>(Wg, Wsoma, Wn1, Wtemp, Wout, bsoma, bn1,
                                                   wg_bf, wsn1, wtemp_bf, wout_bf, bsn1);

  ctx_carry_k<<<dim3(256), dim3(256), 0, stream>>>(x, tau_ctx, car_ctx);
  ctx_scan_k <<<dim3(256), dim3(256), 0, stream>>>(x, tau_ctx, car_ctx, gatein);

  // fused gate | soma | h1 GEMM
  gemm1_k<<<dim3(64, 18), dim3(256), 0, stream>>>(gatein, wg_bf, wsn1, bg, bsn1,
                                                  gated, soma, h1_bf);

  mod_k<<<dim3(M_ROWS/4), dim3(256), 0, stream>>>(h1_bf, Wn2, bn2, modbuf);

  dend_carry_k<<<dim3(256), dim3(256), 0, stream>>>(gated, modbuf, tau_raws, car_d);
  dend_scan_k <<<dim3(256), dim3(256), 0, stream>>>(gated, modbuf, tau_raws, car_d, blend, temporal);

  // sg = soma * sigmoid(temporal@Wtemp^T + btemp)   (overwrites gated)
  gemm_k<2><<<dim3(64, 8), dim3(256), 0, stream>>>(temporal, wtemp_bf, btemp, soma, sg);

  // out_pre = sg@Wout^T   (overwrites gatein)
  gemm_k<3><<<dim3(64, 8), dim3(256), 0, stream>>>(sg, wout_bf, nullptr, nullptr, out_pre);

  ln_k<<<dim3(M_ROWS), dim3(256), 0, stream>>>(out_pre, gamma, beta, (float*)d_out);
}